// Round 8
// baseline (1049.014 us; speedup 1.0000x reference)
//
#include <hip/hip_runtime.h>
#include <math.h>

#define HH 20
#define HS 22      // f64 LDS row stride (rows 16B-aligned: 22*8=176)
#define HSF 21     // f32 LDS row stride (odd -> spreads banks)
#define PP 64

// ---- f64 weight workspace layout (doubles) ----
#define W_WI0 0      // 60
#define W_BI0 60     // 20
#define W_WI1 80     // 400
#define W_BI1 480    // 20
#define W_WI2 500    // 400
#define W_BI2 900    // 20
#define W_EB0 920    // WaD0 0..399 | WaH0 400..799 | Wb0 800..1199 | ba0 1200..1219 | bb0 1220..1239
#define W_F1  2160   // float bundle for blk1: WaD1f 0..399 | WaH1f 400..799 | Wb1f 800..1199 | ba1f 1200.. | bb1f 1220.. (floats)

// compact expm1 for v<=0: rel error ~7e-12, result in (-1,0]
__device__ __forceinline__ double expm1_neg(double v) {
    if (v <= -40.0) return -1.0;
    const double LOG2E  = 1.4426950408889634074e+00;
    const double LN2_HI = 6.93147180369123816490e-01;
    const double LN2_LO = 1.90821492927058770002e-10;
    double nd = rint(v * LOG2E);
    double r  = fma(-nd, LN2_HI, v);
    r = fma(-nd, LN2_LO, r);
    double p = 2.75573192239858925110e-06;          // 1/9!
    p = fma(p, r, 2.48015873015873015873e-05);
    p = fma(p, r, 1.98412698412698412698e-04);
    p = fma(p, r, 1.38888888888888888889e-03);
    p = fma(p, r, 8.33333333333333333333e-03);
    p = fma(p, r, 4.16666666666666666667e-02);
    p = fma(p, r, 1.66666666666666666667e-01);
    p = fma(p, r, 5.0e-01);
    p = fma(p, r, 1.0);
    p = fma(p, r, 1.0);
    long long n = (long long)nd;
    double sc = __builtin_bit_cast(double, (unsigned long long)(1023ll + n) << 52);
    return fma(p, sc, -1.0);
}
__device__ __forceinline__ double elu_d(double v) { return v > 0.0 ? v : expm1_neg(v); }
__device__ __forceinline__ float  elu_f(float v)  { return v > 0.0f ? v : expm1f(v); }
// fast f32 elu for the continuous-only path (abs err ~1e-7)
__device__ __forceinline__ float  elu_fast(float v) { return v > 0.0f ? v : __expf(v) - 1.0f; }

// order-preserving encodings for atomicMax
__device__ __forceinline__ unsigned long long fenc64(double f) {
    unsigned long long u = __builtin_bit_cast(unsigned long long, f);
    return (u & 0x8000000000000000ull) ? ~u : (u | 0x8000000000000000ull);
}
__device__ __forceinline__ double fdec64(unsigned long long u) {
    unsigned long long b = (u & 0x8000000000000000ull) ? (u & 0x7fffffffffffffffull) : ~u;
    return __builtin_bit_cast(double, b);
}
__device__ __forceinline__ unsigned fenc32(float f) {
    unsigned u = __float_as_uint(f);
    return (u & 0x80000000u) ? ~u : (u | 0x80000000u);
}
__device__ __forceinline__ float fdec32(unsigned u) {
    unsigned b = (u & 0x80000000u) ? (u & 0x7fffffffu) : ~u;
    return __uint_as_float(b);
}

__global__ __launch_bounds__(256) void prep_weights(
    const float* __restrict__ Wi0, const float* __restrict__ bi0,
    const float* __restrict__ Wi1, const float* __restrict__ bi1,
    const float* __restrict__ Wi2, const float* __restrict__ bi2,
    const float* __restrict__ We0a, const float* __restrict__ be0a,
    const float* __restrict__ We0b, const float* __restrict__ be0b,
    const float* __restrict__ We1a, const float* __restrict__ be1a,
    const float* __restrict__ We1b, const float* __restrict__ be1b,
    double* __restrict__ ws)
{
    const int t = threadIdx.x;
    float* wf = (float*)(ws + W_F1);
    #define CV(off, src, n) for (int i = t; i < (n); i += 256) ws[(off) + i] = (double)(src)[i];
    CV(W_WI0, Wi0, 60)  CV(W_BI0, bi0, 20)
    CV(W_WI1, Wi1, 400) CV(W_BI1, bi1, 20)
    CV(W_WI2, Wi2, 400) CV(W_BI2, bi2, 20)
    for (int i = t; i < 400; i += 256) {
        ws[W_EB0 +       i] = (double)We0a[i] - (double)We0a[400 + i];
        ws[W_EB0 + 400 + i] = (double)We0a[400 + i];
        ws[W_EB0 + 800 + i] = (double)We0b[i];
        wf[      i] = We1a[i] - We1a[400 + i];
        wf[400 + i] = We1a[400 + i];
        wf[800 + i] = We1b[i];
    }
    for (int i = t; i < 20; i += 256) {
        ws[W_EB0 + 1200 + i] = (double)be0a[i];
        ws[W_EB0 + 1220 + i] = (double)be0b[i];
        wf[1200 + i] = be1a[i];
        wf[1220 + i] = be1b[i];
    }
    #undef CV
}

#define SBAR() __builtin_amdgcn_sched_barrier(0)

__global__ __launch_bounds__(64, 1) void dgcnn_fused(
    const float* __restrict__ x,
    const double* __restrict__ wd,
    const float* __restrict__ Wo0, const float* __restrict__ bo0,
    const float* __restrict__ Wo1, const float* __restrict__ bo1,
    const float* __restrict__ Wo2, const float* __restrict__ bo2,
    float* __restrict__ out)
{
    const int b = blockIdx.x;
    const int p = threadIdx.x;

    __shared__ __align__(16) double hbuf[PP][HS];   // 11264 B; reused as y-rows and pool buffers
    __shared__ int ivld[PP];
    __shared__ int cflag[PP];

    const float* wf = (const float*)(wd + W_F1);

    // ---------------- input MLP: 3 -> 20 -> 20 -> 20 (f64, s_load weights) ----------------
    double h[HH];
    {
        const size_t xb = (size_t)b * (PP * 3) + (size_t)p * 3;
        const double x0 = (double)x[xb + 0];
        const double x1 = (double)x[xb + 1];
        const double x2 = (double)x[xb + 2];
        double t[HH];
        #pragma unroll
        for (int j = 0; j < HH; ++j)
            t[j] = fma(x2, wd[W_WI0 + 2*HH + j],
                   fma(x1, wd[W_WI0 + HH + j],
                   fma(x0, wd[W_WI0 + j], wd[W_BI0 + j])));
        #pragma unroll
        for (int j5 = 0; j5 < HH; j5 += 5) {
            #pragma unroll
            for (int j = j5; j < j5 + 5; ++j) t[j] = elu_d(t[j]);
            SBAR();
        }
        #pragma unroll
        for (int j = 0; j < HH; ++j) h[j] = wd[W_BI1 + j];
        #pragma unroll 2
        for (int d = 0; d < HH; ++d) {
            const double td = t[d];
            #pragma unroll
            for (int j = 0; j < HH; ++j)
                h[j] = fma(td, wd[W_WI1 + d*HH + j], h[j]);
        }
        #pragma unroll
        for (int j5 = 0; j5 < HH; j5 += 5) {
            #pragma unroll
            for (int j = j5; j < j5 + 5; ++j) t[j] = elu_d(h[j]);
            SBAR();
        }
        #pragma unroll
        for (int j = 0; j < HH; ++j) h[j] = wd[W_BI2 + j];
        #pragma unroll 2
        for (int d = 0; d < HH; ++d) {
            const double td = t[d];
            #pragma unroll
            for (int j = 0; j < HH; ++j)
                h[j] = fma(td, wd[W_WI2 + d*HH + j], h[j]);
        }
        #pragma unroll
        for (int j5 = 0; j5 < HH; j5 += 5) {
            #pragma unroll
            for (int j = j5; j < j5 + 5; ++j) h[j] = elu_d(h[j]);
            SBAR();
        }
    }

    // ================= BLOCK 0 : EdgeConv + pool, full f64 (feeds knn1) =================
    int myvalid;   // set by blk0 pool
    int i0_b0;
    {
        double sqp = 0.0;
        #pragma unroll
        for (int d = 0; d < HH; ++d) sqp = fma(h[d], h[d], sqp);
        #pragma unroll
        for (int j = 0; j < HH; ++j) hbuf[p][j] = h[j];
        hbuf[p][HH] = sqp;
        __syncthreads();

        // knn0: all points valid; mask only q==p
        unsigned long long e0 = 0ull, e1 = 0ull, e2 = 0ull, e3 = 0ull;
        #pragma unroll 2
        for (int q = 0; q < PP; ++q) {
            const double2* rowq = (const double2*)&hbuf[q][0];
            double a0 = 0.0, a1 = 0.0, a2 = 0.0, a3 = 0.0;
            #pragma unroll
            for (int t2 = 0; t2 < 10; t2 += 2) {
                const double2 r0 = rowq[t2];
                const double2 r1 = rowq[t2 + 1];
                a0 = fma(r0.x, h[2*t2],     a0);
                a1 = fma(r0.y, h[2*t2 + 1], a1);
                a2 = fma(r1.x, h[2*t2 + 2], a2);
                a3 = fma(r1.y, h[2*t2 + 3], a3);
            }
            double s = 2.0*((a0 + a1) + (a2 + a3)) - sqp - hbuf[q][HH];
            if (q == p) s = -INFINITY;
            const unsigned long long e =
                (fenc64(s) & ~63ull) | (unsigned long long)(63 - q);
            const bool b0 = e > e0;
            const bool b1 = e > e1;
            const bool b2 = e > e2;
            const bool b3 = e > e3;
            e3 = b2 ? e2 : (b3 ? e : e3);
            e2 = b1 ? e1 : (b2 ? e : e2);
            e1 = b0 ? e0 : (b1 ? e : e1);
            e0 = b0 ? e  : e0;
        }
        SBAR();
        i0_b0 = 63 - (int)(e0 & 63ull);

        // base = ba + h @ (Wa_xi - Wa_xj); y = h @ Wa_xj  (weights via s_load)
        double base[HH], y[HH];
        #pragma unroll
        for (int j = 0; j < HH; ++j) base[j] = wd[W_EB0 + 1200 + j];
        #pragma unroll 2
        for (int d = 0; d < HH; ++d) {
            const double hd = h[d];
            #pragma unroll
            for (int j = 0; j < HH; ++j)
                base[j] = fma(hd, wd[W_EB0 + d*HH + j], base[j]);
        }
        #pragma unroll
        for (int j = 0; j < HH; ++j) y[j] = 0.0;
        #pragma unroll 2
        for (int d = 0; d < HH; ++d) {
            const double hd = h[d];
            #pragma unroll
            for (int j = 0; j < HH; ++j)
                y[j] = fma(hd, wd[W_EB0 + 400 + d*HH + j], y[j]);
        }
        __syncthreads();           // done reading h rows
        #pragma unroll
        for (int j = 0; j < HH; ++j) hbuf[p][j] = y[j];
        __syncthreads();

        double hsum[HH];
        #pragma unroll
        for (int j = 0; j < HH; ++j) hsum[j] = 0.0;

        #pragma unroll 1
        for (int k = 0; k < 4; ++k) {
            const unsigned long long ek = (k == 0) ? e0 : (k == 1) ? e1 : (k == 2) ? e2 : e3;
            const int jn = 63 - (int)(ek & 63ull);

            double m1[HH];
            #pragma unroll
            for (int j = 0; j < HH; ++j) m1[j] = base[j] + hbuf[jn][j];
            #pragma unroll
            for (int j5 = 0; j5 < HH; j5 += 5) {
                #pragma unroll
                for (int j = j5; j < j5 + 5; ++j) m1[j] = elu_d(m1[j]);
                SBAR();
            }
            #pragma unroll
            for (int j5 = 0; j5 < HH; j5 += 5) {
                #pragma unroll
                for (int j = j5; j < j5 + 5; ++j) {
                    double a0 = wd[W_EB0 + 1220 + j];
                    #pragma unroll
                    for (int d = 0; d < HH; ++d)
                        a0 = fma(m1[d], wd[W_EB0 + 800 + d*HH + j], a0);
                    hsum[j] += elu_d(a0);          // all neighbors valid in blk0
                }
                SBAR();
            }
        }
        __syncthreads();           // done reading y rows

        // pool (u64-encoded f64 scatter-max)
        unsigned long long* pbuf = (unsigned long long*)&hbuf[0][0];
        #pragma unroll
        for (int j = 0; j < HH; ++j) pbuf[p*HS + j] = 0ull;
        cflag[p] = 0;
        __syncthreads();
        {
            const int c = min(p, i0_b0);
            cflag[c] = 1;                          // benign same-value race
            #pragma unroll
            for (int j = 0; j < HH; ++j)
                atomicMax(&pbuf[c*HS + j], fenc64(hsum[j]));
        }
        __syncthreads();
        {
            const int nv = cflag[p];
            myvalid = nv;
            #pragma unroll
            for (int j = 0; j < HH; ++j)
                h[j] = nv ? fdec64(pbuf[p*HS + j]) : 0.0;
        }
        __syncthreads();
    }

    // ================= BLOCK 1 : knn f64, EdgeConv + pool f32 (continuous only) =================
    float hpool[HH];   // blk1 pooled output (f32)
    int   vfinal;
    {
        double sqp = 0.0;
        #pragma unroll
        for (int d = 0; d < HH; ++d) sqp = fma(h[d], h[d], sqp);
        #pragma unroll
        for (int j = 0; j < HH; ++j) hbuf[p][j] = h[j];
        hbuf[p][HH] = sqp;
        ivld[p] = myvalid;
        __syncthreads();

        unsigned long long e0 = 0ull, e1 = 0ull, e2 = 0ull, e3 = 0ull;
        #pragma unroll 2
        for (int q = 0; q < PP; ++q) {
            const double2* rowq = (const double2*)&hbuf[q][0];
            double a0 = 0.0, a1 = 0.0, a2 = 0.0, a3 = 0.0;
            #pragma unroll
            for (int t2 = 0; t2 < 10; t2 += 2) {
                const double2 r0 = rowq[t2];
                const double2 r1 = rowq[t2 + 1];
                a0 = fma(r0.x, h[2*t2],     a0);
                a1 = fma(r0.y, h[2*t2 + 1], a1);
                a2 = fma(r1.x, h[2*t2 + 2], a2);
                a3 = fma(r1.y, h[2*t2 + 3], a3);
            }
            double s = 2.0*((a0 + a1) + (a2 + a3)) - sqp - hbuf[q][HH];
            if (q == p || ivld[q] == 0) s = -INFINITY;
            const unsigned long long e =
                (fenc64(s) & ~63ull) | (unsigned long long)(63 - q);
            const bool b0 = e > e0;
            const bool b1 = e > e1;
            const bool b2 = e > e2;
            const bool b3 = e > e3;
            e3 = b2 ? e2 : (b3 ? e : e3);
            e2 = b1 ? e1 : (b2 ? e : e2);
            e1 = b0 ? e0 : (b1 ? e : e1);
            e0 = b0 ? e  : e0;
        }
        SBAR();
        const int i0 = 63 - (int)(e0 & 63ull);

        // f32 from here: feeds only final max + output MLP
        float hf[HH];
        #pragma unroll
        for (int j = 0; j < HH; ++j) hf[j] = (float)h[j];

        float basef[HH], yf[HH];
        #pragma unroll
        for (int j = 0; j < HH; ++j) basef[j] = wf[1200 + j];
        #pragma unroll 2
        for (int d = 0; d < HH; ++d) {
            const float hd = hf[d];
            #pragma unroll
            for (int j = 0; j < HH; ++j)
                basef[j] = fmaf(hd, wf[d*HH + j], basef[j]);
        }
        #pragma unroll
        for (int j = 0; j < HH; ++j) yf[j] = 0.0f;
        #pragma unroll 2
        for (int d = 0; d < HH; ++d) {
            const float hd = hf[d];
            #pragma unroll
            for (int j = 0; j < HH; ++j)
                yf[j] = fmaf(hd, wf[400 + d*HH + j], yf[j]);
        }
        __syncthreads();           // done reading h rows
        float* ybuf = (float*)&hbuf[0][0];
        #pragma unroll
        for (int j = 0; j < HH; ++j) ybuf[p*HSF + j] = yf[j];
        __syncthreads();

        float hsumf[HH];
        #pragma unroll
        for (int j = 0; j < HH; ++j) hsumf[j] = 0.0f;

        #pragma unroll 1
        for (int k = 0; k < 4; ++k) {
            const unsigned long long ek = (k == 0) ? e0 : (k == 1) ? e1 : (k == 2) ? e2 : e3;
            const int jn = 63 - (int)(ek & 63ull);
            const float vn = (float)ivld[jn];

            float m1f[HH];
            #pragma unroll
            for (int j = 0; j < HH; ++j) m1f[j] = elu_fast(basef[j] + ybuf[jn*HSF + j]);
            #pragma unroll
            for (int j = 0; j < HH; ++j) {
                float a0 = wf[1220 + j];
                #pragma unroll
                for (int d = 0; d < HH; ++d)
                    a0 = fmaf(m1f[d], wf[800 + d*HH + j], a0);
                hsumf[j] = fmaf(elu_fast(a0), vn, hsumf[j]);
            }
        }
        {
            const float vp = (float)myvalid;
            #pragma unroll
            for (int j = 0; j < HH; ++j) hsumf[j] *= vp;
        }
        __syncthreads();           // done reading y rows

        // pool (u32-encoded f32 scatter-max)
        unsigned* pb32 = (unsigned*)&hbuf[0][0];
        #pragma unroll
        for (int j = 0; j < HH; ++j) pb32[p*HSF + j] = 0u;
        cflag[p] = 0;
        __syncthreads();
        {
            const int c = min(p, i0);
            if (myvalid) {
                cflag[c] = 1;
                #pragma unroll
                for (int j = 0; j < HH; ++j)
                    atomicMax(&pb32[c*HSF + j], fenc32(hsumf[j]));
            }
        }
        __syncthreads();
        {
            vfinal = cflag[p];
            #pragma unroll
            for (int j = 0; j < HH; ++j)
                hpool[j] = vfinal ? fdec32(pb32[p*HSF + j]) : 0.0f;
        }
    }

    // ---------------- global max + output MLP + log_softmax (f32) ----------------
    float hf[HH];
    #pragma unroll
    for (int j = 0; j < HH; ++j) hf[j] = vfinal ? hpool[j] : -INFINITY;
    #pragma unroll
    for (int s = 1; s < 64; s <<= 1) {
        #pragma unroll
        for (int j = 0; j < HH; ++j)
            hf[j] = fmaxf(hf[j], __shfl_xor(hf[j], s));
    }

    float o1[HH], o2[HH], lg[10];
    #pragma unroll
    for (int j = 0; j < HH; ++j) o1[j] = bo0[j];
    #pragma unroll 2
    for (int d = 0; d < HH; ++d) {
        #pragma unroll
        for (int j = 0; j < HH; ++j) o1[j] = fmaf(hf[d], Wo0[d*HH + j], o1[j]);
    }
    #pragma unroll
    for (int j = 0; j < HH; ++j) o1[j] = elu_f(o1[j]);
    #pragma unroll
    for (int j = 0; j < HH; ++j) o2[j] = bo1[j];
    #pragma unroll 2
    for (int d = 0; d < HH; ++d) {
        #pragma unroll
        for (int j = 0; j < HH; ++j) o2[j] = fmaf(o1[d], Wo1[d*HH + j], o2[j]);
    }
    #pragma unroll
    for (int j = 0; j < HH; ++j) o2[j] = elu_f(o2[j]);
    #pragma unroll
    for (int j = 0; j < 10; ++j) lg[j] = bo2[j];
    #pragma unroll 2
    for (int d = 0; d < HH; ++d) {
        #pragma unroll
        for (int j = 0; j < 10; ++j) lg[j] = fmaf(o2[d], Wo2[d*10 + j], lg[j]);
    }
    float m = lg[0];
    #pragma unroll
    for (int j = 1; j < 10; ++j) m = fmaxf(m, lg[j]);
    float ssum = 0.0f;
    #pragma unroll
    for (int j = 0; j < 10; ++j) ssum += expf(lg[j] - m);
    const float lse = m + logf(ssum);
    if (p < 10) {
        float v = 0.0f;
        #pragma unroll
        for (int j = 0; j < 10; ++j) v = (p == j) ? lg[j] : v;
        out[(size_t)b * 10 + p] = v - lse;
    }
}

extern "C" void kernel_launch(void* const* d_in, const int* in_sizes, int n_in,
                              void* d_out, int out_size, void* d_ws, size_t ws_size,
                              hipStream_t stream) {
    const float* x    = (const float*)d_in[0];
    const float* Wi0  = (const float*)d_in[1];
    const float* bi0  = (const float*)d_in[2];
    const float* Wi1  = (const float*)d_in[3];
    const float* bi1  = (const float*)d_in[4];
    const float* Wi2  = (const float*)d_in[5];
    const float* bi2  = (const float*)d_in[6];
    const float* We0a = (const float*)d_in[7];
    const float* be0a = (const float*)d_in[8];
    const float* We0b = (const float*)d_in[9];
    const float* be0b = (const float*)d_in[10];
    const float* We1a = (const float*)d_in[11];
    const float* be1a = (const float*)d_in[12];
    const float* We1b = (const float*)d_in[13];
    const float* be1b = (const float*)d_in[14];
    const float* Wo0  = (const float*)d_in[15];
    const float* bo0  = (const float*)d_in[16];
    const float* Wo1  = (const float*)d_in[17];
    const float* bo1  = (const float*)d_in[18];
    const float* Wo2  = (const float*)d_in[19];
    const float* bo2  = (const float*)d_in[20];
    float* out = (float*)d_out;
    double* ws = (double*)d_ws;

    prep_weights<<<dim3(1), dim3(256), 0, stream>>>(
        Wi0, bi0, Wi1, bi1, Wi2, bi2,
        We0a, be0a, We0b, be0b, We1a, be1a, We1b, be1b, ws);

    dgcnn_fused<<<dim3(8192), dim3(64), 0, stream>>>(
        x, ws, Wo0, bo0, Wo1, bo1, Wo2, bo2, out);
}

// Round 9
// 989.383 us; speedup vs baseline: 1.0603x; 1.0603x over previous
//
#include <hip/hip_runtime.h>
#include <math.h>

#define HH 20
#define HS 22      // f64 LDS row stride (rows 16B-aligned)
#define HSF 21     // f32 LDS row stride
#define PP 64

// ---- f64 weight workspace layout (doubles) ----
#define W_WI0 0      // 60
#define W_BI0 60     // 20
#define W_WI1 80     // 400   } contiguous 840-double run 80..919
#define W_BI1 480    // 20    }
#define W_WI2 500    // 400   }
#define W_BI2 900    // 20    }
#define W_EB0 920    // 1240: WaD0 | WaH0(+400) | Wb0(+800) | ba0(+1200) | bb0(+1220)
#define W_F1  2160   // float bundle for blk1 (1240 floats): WaD1f | WaH1f | Wb1f | ba1f | bb1f

// compact expm1 for v<=0: rel error ~7e-12, result in (-1,0]
__device__ __forceinline__ double expm1_neg(double v) {
    if (v <= -40.0) return -1.0;
    const double LOG2E  = 1.4426950408889634074e+00;
    const double LN2_HI = 6.93147180369123816490e-01;
    const double LN2_LO = 1.90821492927058770002e-10;
    double nd = rint(v * LOG2E);
    double r  = fma(-nd, LN2_HI, v);
    r = fma(-nd, LN2_LO, r);
    double p = 2.75573192239858925110e-06;          // 1/9!
    p = fma(p, r, 2.48015873015873015873e-05);
    p = fma(p, r, 1.98412698412698412698e-04);
    p = fma(p, r, 1.38888888888888888889e-03);
    p = fma(p, r, 8.33333333333333333333e-03);
    p = fma(p, r, 4.16666666666666666667e-02);
    p = fma(p, r, 1.66666666666666666667e-01);
    p = fma(p, r, 5.0e-01);
    p = fma(p, r, 1.0);
    p = fma(p, r, 1.0);
    long long n = (long long)nd;
    double sc = __builtin_bit_cast(double, (unsigned long long)(1023ll + n) << 52);
    return fma(p, sc, -1.0);
}
__device__ __forceinline__ double elu_d(double v) { return v > 0.0 ? v : expm1_neg(v); }
__device__ __forceinline__ float  elu_f(float v)  { return v > 0.0f ? v : expm1f(v); }
__device__ __forceinline__ float  elu_fast(float v) { return v > 0.0f ? v : __expf(v) - 1.0f; }

// order-preserving encodings for atomicMax
__device__ __forceinline__ unsigned long long fenc64(double f) {
    unsigned long long u = __builtin_bit_cast(unsigned long long, f);
    return (u & 0x8000000000000000ull) ? ~u : (u | 0x8000000000000000ull);
}
__device__ __forceinline__ double fdec64(unsigned long long u) {
    unsigned long long b = (u & 0x8000000000000000ull) ? (u & 0x7fffffffffffffffull) : ~u;
    return __builtin_bit_cast(double, b);
}
__device__ __forceinline__ unsigned fenc32(float f) {
    unsigned u = __float_as_uint(f);
    return (u & 0x80000000u) ? ~u : (u | 0x80000000u);
}
__device__ __forceinline__ float fdec32(unsigned u) {
    unsigned b = (u & 0x80000000u) ? (u & 0x7fffffffu) : ~u;
    return __uint_as_float(b);
}

__global__ __launch_bounds__(256) void prep_weights(
    const float* __restrict__ Wi0, const float* __restrict__ bi0,
    const float* __restrict__ Wi1, const float* __restrict__ bi1,
    const float* __restrict__ Wi2, const float* __restrict__ bi2,
    const float* __restrict__ We0a, const float* __restrict__ be0a,
    const float* __restrict__ We0b, const float* __restrict__ be0b,
    const float* __restrict__ We1a, const float* __restrict__ be1a,
    const float* __restrict__ We1b, const float* __restrict__ be1b,
    double* __restrict__ ws)
{
    const int t = threadIdx.x;
    float* wf = (float*)(ws + W_F1);
    #define CV(off, src, n) for (int i = t; i < (n); i += 256) ws[(off) + i] = (double)(src)[i];
    CV(W_WI0, Wi0, 60)  CV(W_BI0, bi0, 20)
    CV(W_WI1, Wi1, 400) CV(W_BI1, bi1, 20)
    CV(W_WI2, Wi2, 400) CV(W_BI2, bi2, 20)
    for (int i = t; i < 400; i += 256) {
        ws[W_EB0 +       i] = (double)We0a[i] - (double)We0a[400 + i];
        ws[W_EB0 + 400 + i] = (double)We0a[400 + i];
        ws[W_EB0 + 800 + i] = (double)We0b[i];
        wf[      i] = We1a[i] - We1a[400 + i];
        wf[400 + i] = We1a[400 + i];
        wf[800 + i] = We1b[i];
    }
    for (int i = t; i < 20; i += 256) {
        ws[W_EB0 + 1200 + i] = (double)be0a[i];
        ws[W_EB0 + 1220 + i] = (double)be0b[i];
        wf[1200 + i] = be1a[i];
        wf[1220 + i] = be1b[i];
    }
    #undef CV
}

#define SBAR() __builtin_amdgcn_sched_barrier(0)

__global__ __launch_bounds__(64, 1) void dgcnn_fused(
    const float* __restrict__ x,
    const double* __restrict__ wd,
    const float* __restrict__ Wo0, const float* __restrict__ bo0,
    const float* __restrict__ Wo1, const float* __restrict__ bo1,
    const float* __restrict__ Wo2, const float* __restrict__ bo2,
    float* __restrict__ out)
{
    const int b = blockIdx.x;
    const int p = threadIdx.x;

    __shared__ __align__(16) double hbuf[PP][HS];   // 11264 B; reused as y rows + pool buffers
    __shared__ __align__(16) double wlds[1240];     // 9920 B; staged 3x (A: input MLP, B: blk0 f64, C: blk1 f32)
    __shared__ int ivld[PP];
    __shared__ int cflag[PP];

    const float* wf = (const float*)(wd + W_F1);
    float* wldsf = (float*)&wlds[0];

    // ---- stage A: Wi1|bi1|Wi2|bi2 (contiguous 840 doubles at wd+80) ----
    // layout in wlds: Wi1 @0, bi1 @400, Wi2 @420, bi2 @820
    for (int i = p; i < 840; i += 64) wlds[i] = wd[80 + i];
    __syncthreads();

    // ---------------- input MLP: 3 -> 20 -> 20 -> 20 (f64) ----------------
    double h[HH];
    {
        const size_t xb = (size_t)b * (PP * 3) + (size_t)p * 3;
        const double x0 = (double)x[xb + 0];
        const double x1 = (double)x[xb + 1];
        const double x2 = (double)x[xb + 2];
        double t[HH];
        #pragma unroll
        for (int j = 0; j < HH; ++j)
            t[j] = fma(x2, wd[W_WI0 + 2*HH + j],
                   fma(x1, wd[W_WI0 + HH + j],
                   fma(x0, wd[W_WI0 + j], wd[W_BI0 + j])));
        #pragma unroll
        for (int j5 = 0; j5 < HH; j5 += 5) {
            #pragma unroll
            for (int j = j5; j < j5 + 5; ++j) t[j] = elu_d(t[j]);
            SBAR();
        }
        #pragma unroll
        for (int j = 0; j < HH; ++j) h[j] = wlds[400 + j];          // bi1
        #pragma unroll 2
        for (int d = 0; d < HH; ++d) {
            const double td = t[d];
            #pragma unroll
            for (int j = 0; j < HH; ++j)
                h[j] = fma(td, wlds[d*HH + j], h[j]);               // Wi1
        }
        #pragma unroll
        for (int j5 = 0; j5 < HH; j5 += 5) {
            #pragma unroll
            for (int j = j5; j < j5 + 5; ++j) t[j] = elu_d(h[j]);
            SBAR();
        }
        #pragma unroll
        for (int j = 0; j < HH; ++j) h[j] = wlds[820 + j];          // bi2
        #pragma unroll 2
        for (int d = 0; d < HH; ++d) {
            const double td = t[d];
            #pragma unroll
            for (int j = 0; j < HH; ++j)
                h[j] = fma(td, wlds[420 + d*HH + j], h[j]);         // Wi2
        }
        #pragma unroll
        for (int j5 = 0; j5 < HH; j5 += 5) {
            #pragma unroll
            for (int j = j5; j < j5 + 5; ++j) h[j] = elu_d(h[j]);
            SBAR();
        }
    }

    // ================= BLOCK 0 : EdgeConv + pool, full f64 (feeds knn1) =================
    int myvalid;
    int i0_b0;
    {
        double sqp = 0.0;
        #pragma unroll
        for (int d = 0; d < HH; ++d) sqp = fma(h[d], h[d], sqp);
        #pragma unroll
        for (int j = 0; j < HH; ++j) hbuf[p][j] = h[j];
        hbuf[p][HH] = sqp;
        __syncthreads();      // hbuf ready; all lanes done with wlds-A

        // ---- stage B (blk0 f64 bundle) overlapped with knn0 ----
        for (int i = p; i < 1240; i += 64) wlds[i] = wd[W_EB0 + i];

        // knn0: all points valid; mask only q==p
        unsigned long long e0 = 0ull, e1 = 0ull, e2 = 0ull, e3 = 0ull;
        #pragma unroll 2
        for (int q = 0; q < PP; ++q) {
            const double2* rowq = (const double2*)&hbuf[q][0];
            double a0 = 0.0, a1 = 0.0, a2 = 0.0, a3 = 0.0;
            #pragma unroll
            for (int t2 = 0; t2 < 10; t2 += 2) {
                const double2 r0 = rowq[t2];
                const double2 r1 = rowq[t2 + 1];
                a0 = fma(r0.x, h[2*t2],     a0);
                a1 = fma(r0.y, h[2*t2 + 1], a1);
                a2 = fma(r1.x, h[2*t2 + 2], a2);
                a3 = fma(r1.y, h[2*t2 + 3], a3);
            }
            double s = 2.0*((a0 + a1) + (a2 + a3)) - sqp - hbuf[q][HH];
            if (q == p) s = -INFINITY;
            const unsigned long long e =
                (fenc64(s) & ~63ull) | (unsigned long long)(63 - q);
            const bool b0 = e > e0;
            const bool b1 = e > e1;
            const bool b2 = e > e2;
            const bool b3 = e > e3;
            e3 = b2 ? e2 : (b3 ? e : e3);
            e2 = b1 ? e1 : (b2 ? e : e2);
            e1 = b0 ? e0 : (b1 ? e : e1);
            e0 = b0 ? e  : e0;
        }
        SBAR();
        i0_b0 = 63 - (int)(e0 & 63ull);
        __syncthreads();      // wlds-B ready; knn hbuf reads done

        // base = ba + h @ (Wa_xi - Wa_xj); y = h @ Wa_xj  (LDS weights)
        double base[HH], y[HH];
        #pragma unroll
        for (int j = 0; j < HH; ++j) base[j] = wlds[1200 + j];
        #pragma unroll 2
        for (int d = 0; d < HH; ++d) {
            const double hd = h[d];
            #pragma unroll
            for (int j = 0; j < HH; ++j)
                base[j] = fma(hd, wlds[d*HH + j], base[j]);
        }
        #pragma unroll
        for (int j = 0; j < HH; ++j) y[j] = 0.0;
        #pragma unroll 2
        for (int d = 0; d < HH; ++d) {
            const double hd = h[d];
            #pragma unroll
            for (int j = 0; j < HH; ++j)
                y[j] = fma(hd, wlds[400 + d*HH + j], y[j]);
        }
        #pragma unroll
        for (int j = 0; j < HH; ++j) hbuf[p][j] = y[j];
        __syncthreads();

        double hsum[HH];
        #pragma unroll
        for (int j = 0; j < HH; ++j) hsum[j] = 0.0;

        #pragma unroll 1
        for (int k = 0; k < 4; ++k) {
            const unsigned long long ek = (k == 0) ? e0 : (k == 1) ? e1 : (k == 2) ? e2 : e3;
            const int jn = 63 - (int)(ek & 63ull);

            double m1[HH];
            #pragma unroll
            for (int j = 0; j < HH; ++j) m1[j] = base[j] + hbuf[jn][j];
            #pragma unroll
            for (int j5 = 0; j5 < HH; j5 += 5) {
                #pragma unroll
                for (int j = j5; j < j5 + 5; ++j) m1[j] = elu_d(m1[j]);
                SBAR();
            }
            #pragma unroll
            for (int j5 = 0; j5 < HH; j5 += 5) {
                #pragma unroll
                for (int j = j5; j < j5 + 5; ++j) {
                    double a0 = wlds[1220 + j];
                    #pragma unroll
                    for (int d = 0; d < HH; ++d)
                        a0 = fma(m1[d], wlds[800 + d*HH + j], a0);
                    hsum[j] += elu_d(a0);          // all neighbors valid in blk0
                }
                SBAR();
            }
        }
        __syncthreads();      // done reading y rows

        // pool (u64-encoded f64 scatter-max)
        unsigned long long* pbuf = (unsigned long long*)&hbuf[0][0];
        #pragma unroll
        for (int j = 0; j < HH; ++j) pbuf[p*HS + j] = 0ull;
        cflag[p] = 0;
        __syncthreads();
        {
            const int c = min(p, i0_b0);
            cflag[c] = 1;                          // benign same-value race
            #pragma unroll
            for (int j = 0; j < HH; ++j)
                atomicMax(&pbuf[c*HS + j], fenc64(hsum[j]));
        }
        __syncthreads();
        {
            const int nv = cflag[p];
            myvalid = nv;
            #pragma unroll
            for (int j = 0; j < HH; ++j)
                h[j] = nv ? fdec64(pbuf[p*HS + j]) : 0.0;
        }
    }

    // ================= BLOCK 1 : knn f64, EdgeConv + pool f32 =================
    float hpool[HH];
    int   vfinal;
    {
        double sqp = 0.0;
        #pragma unroll
        for (int d = 0; d < HH; ++d) sqp = fma(h[d], h[d], sqp);
        #pragma unroll
        for (int j = 0; j < HH; ++j) hbuf[p][j] = h[j];   // own row (pool readback was own-row too)
        hbuf[p][HH] = sqp;
        ivld[p] = myvalid;
        __syncthreads();

        // ---- stage C (blk1 f32 bundle) overlapped with knn1 ----
        for (int i = p; i < 1240; i += 64) wldsf[i] = wf[i];

        unsigned long long e0 = 0ull, e1 = 0ull, e2 = 0ull, e3 = 0ull;
        #pragma unroll 2
        for (int q = 0; q < PP; ++q) {
            const double2* rowq = (const double2*)&hbuf[q][0];
            double a0 = 0.0, a1 = 0.0, a2 = 0.0, a3 = 0.0;
            #pragma unroll
            for (int t2 = 0; t2 < 10; t2 += 2) {
                const double2 r0 = rowq[t2];
                const double2 r1 = rowq[t2 + 1];
                a0 = fma(r0.x, h[2*t2],     a0);
                a1 = fma(r0.y, h[2*t2 + 1], a1);
                a2 = fma(r1.x, h[2*t2 + 2], a2);
                a3 = fma(r1.y, h[2*t2 + 3], a3);
            }
            double s = 2.0*((a0 + a1) + (a2 + a3)) - sqp - hbuf[q][HH];
            if (q == p || ivld[q] == 0) s = -INFINITY;
            const unsigned long long e =
                (fenc64(s) & ~63ull) | (unsigned long long)(63 - q);
            const bool b0 = e > e0;
            const bool b1 = e > e1;
            const bool b2 = e > e2;
            const bool b3 = e > e3;
            e3 = b2 ? e2 : (b3 ? e : e3);
            e2 = b1 ? e1 : (b2 ? e : e2);
            e1 = b0 ? e0 : (b1 ? e : e1);
            e0 = b0 ? e  : e0;
        }
        SBAR();
        const int i0 = 63 - (int)(e0 & 63ull);
        __syncthreads();      // wlds-C ready; knn hbuf reads done

        float hf[HH];
        #pragma unroll
        for (int j = 0; j < HH; ++j) hf[j] = (float)h[j];

        float basef[HH], yf[HH];
        #pragma unroll
        for (int j = 0; j < HH; ++j) basef[j] = wldsf[1200 + j];
        #pragma unroll 2
        for (int d = 0; d < HH; ++d) {
            const float hd = hf[d];
            #pragma unroll
            for (int j = 0; j < HH; ++j)
                basef[j] = fmaf(hd, wldsf[d*HH + j], basef[j]);
        }
        #pragma unroll
        for (int j = 0; j < HH; ++j) yf[j] = 0.0f;
        #pragma unroll 2
        for (int d = 0; d < HH; ++d) {
            const float hd = hf[d];
            #pragma unroll
            for (int j = 0; j < HH; ++j)
                yf[j] = fmaf(hd, wldsf[400 + d*HH + j], yf[j]);
        }
        float* ybuf = (float*)&hbuf[0][0];
        #pragma unroll
        for (int j = 0; j < HH; ++j) ybuf[p*HSF + j] = yf[j];
        __syncthreads();

        float hsumf[HH];
        #pragma unroll
        for (int j = 0; j < HH; ++j) hsumf[j] = 0.0f;

        #pragma unroll 1
        for (int k = 0; k < 4; ++k) {
            const unsigned long long ek = (k == 0) ? e0 : (k == 1) ? e1 : (k == 2) ? e2 : e3;
            const int jn = 63 - (int)(ek & 63ull);
            const float vn = (float)ivld[jn];

            float m1f[HH];
            #pragma unroll
            for (int j = 0; j < HH; ++j) m1f[j] = elu_fast(basef[j] + ybuf[jn*HSF + j]);
            #pragma unroll
            for (int j = 0; j < HH; ++j) {
                float a0 = wldsf[1220 + j];
                #pragma unroll
                for (int d = 0; d < HH; ++d)
                    a0 = fmaf(m1f[d], wldsf[800 + d*HH + j], a0);
                hsumf[j] = fmaf(elu_fast(a0), vn, hsumf[j]);
            }
        }
        {
            const float vp = (float)myvalid;
            #pragma unroll
            for (int j = 0; j < HH; ++j) hsumf[j] *= vp;
        }
        __syncthreads();      // done reading y rows

        // pool (u32-encoded f32 scatter-max)
        unsigned* pb32 = (unsigned*)&hbuf[0][0];
        #pragma unroll
        for (int j = 0; j < HH; ++j) pb32[p*HSF + j] = 0u;
        cflag[p] = 0;
        __syncthreads();
        {
            const int c = min(p, i0);
            if (myvalid) {
                cflag[c] = 1;
                #pragma unroll
                for (int j = 0; j < HH; ++j)
                    atomicMax(&pb32[c*HSF + j], fenc32(hsumf[j]));
            }
        }
        __syncthreads();
        {
            vfinal = cflag[p];
            #pragma unroll
            for (int j = 0; j < HH; ++j)
                hpool[j] = vfinal ? fdec32(pb32[p*HSF + j]) : 0.0f;
        }
    }

    // ---------------- global max + output MLP + log_softmax (f32) ----------------
    float hf[HH];
    #pragma unroll
    for (int j = 0; j < HH; ++j) hf[j] = vfinal ? hpool[j] : -INFINITY;
    #pragma unroll
    for (int s = 1; s < 64; s <<= 1) {
        #pragma unroll
        for (int j = 0; j < HH; ++j)
            hf[j] = fmaxf(hf[j], __shfl_xor(hf[j], s));
    }

    float o1[HH], o2[HH], lg[10];
    #pragma unroll
    for (int j = 0; j < HH; ++j) o1[j] = bo0[j];
    #pragma unroll 2
    for (int d = 0; d < HH; ++d) {
        #pragma unroll
        for (int j = 0; j < HH; ++j) o1[j] = fmaf(hf[d], Wo0[d*HH + j], o1[j]);
    }
    #pragma unroll
    for (int j = 0; j < HH; ++j) o1[j] = elu_f(o1[j]);
    #pragma unroll
    for (int j = 0; j < HH; ++j) o2[j] = bo1[j];
    #pragma unroll 2
    for (int d = 0; d < HH; ++d) {
        #pragma unroll
        for (int j = 0; j < HH; ++j) o2[j] = fmaf(o1[d], Wo1[d*HH + j], o2[j]);
    }
    #pragma unroll
    for (int j = 0; j < HH; ++j) o2[j] = elu_f(o2[j]);
    #pragma unroll
    for (int j = 0; j < 10; ++j) lg[j] = bo2[j];
    #pragma unroll 2
    for (int d = 0; d < HH; ++d) {
        #pragma unroll
        for (int j = 0; j < 10; ++j) lg[j] = fmaf(o2[d], Wo2[d*10 + j], lg[j]);
    }
    float m = lg[0];
    #pragma unroll
    for (int j = 1; j < 10; ++j) m = fmaxf(m, lg[j]);
    float ssum = 0.0f;
    #pragma unroll
    for (int j = 0; j < 10; ++j) ssum += expf(lg[j] - m);
    const float lse = m + logf(ssum);
    if (p < 10) {
        float v = 0.0f;
        #pragma unroll
        for (int j = 0; j < 10; ++j) v = (p == j) ? lg[j] : v;
        out[(size_t)b * 10 + p] = v - lse;
    }
}

extern "C" void kernel_launch(void* const* d_in, const int* in_sizes, int n_in,
                              void* d_out, int out_size, void* d_ws, size_t ws_size,
                              hipStream_t stream) {
    const float* x    = (const float*)d_in[0];
    const float* Wi0  = (const float*)d_in[1];
    const float* bi0  = (const float*)d_in[2];
    const float* Wi1  = (const float*)d_in[3];
    const float* bi1  = (const float*)d_in[4];
    const float* Wi2  = (const float*)d_in[5];
    const float* bi2  = (const float*)d_in[6];
    const float* We0a = (const float*)d_in[7];
    const float* be0a = (const float*)d_in[8];
    const float* We0b = (const float*)d_in[9];
    const float* be0b = (const float*)d_in[10];
    const float* We1a = (const float*)d_in[11];
    const float* be1a = (const float*)d_in[12];
    const float* We1b = (const float*)d_in[13];
    const float* be1b = (const float*)d_in[14];
    const float* Wo0  = (const float*)d_in[15];
    const float* bo0  = (const float*)d_in[16];
    const float* Wo1  = (const float*)d_in[17];
    const float* bo1  = (const float*)d_in[18];
    const float* Wo2  = (const float*)d_in[19];
    const float* bo2  = (const float*)d_in[20];
    float* out = (float*)d_out;
    double* ws = (double*)d_ws;

    prep_weights<<<dim3(1), dim3(256), 0, stream>>>(
        Wi0, bi0, Wi1, bi1, Wi2, bi2,
        We0a, be0a, We0b, be0b, We1a, be1a, We1b, be1b, ws);

    dgcnn_fused<<<dim3(8192), dim3(64), 0, stream>>>(
        x, ws, Wo0, bo0, Wo1, bo1, Wo2, bo2, out);
}